// Round 1
// baseline (303.502 us; speedup 1.0000x reference)
//
#include <hip/hip_runtime.h>
#include <stdint.h>

#define N_NODES 2048
#define N_EDGES 4096
#define N_GRAPH 16
#define IN_DIM  11
#define HID     128
#define E_DIMF  6
#define EDGE_H  64
#define NSLICE  65            // 64 h-slices + 1 bias slice
#define ZCOLS   (NSLICE*HID)  // 8320
#define BN_EPS  1e-5f

typedef __attribute__((ext_vector_type(8))) short short8;
typedef __attribute__((ext_vector_type(4))) float f32x4;

static __device__ __forceinline__ float bf2f(unsigned short u) {
  union { float f; uint32_t i; } x; x.i = ((uint32_t)u) << 16; return x.f;
}
static __device__ __forceinline__ unsigned short f2bf(float f) {
  union { float f; uint32_t i; } x; x.f = f;
  uint32_t i = x.i;
  return (unsigned short)((i + 0x7FFFu + ((i >> 16) & 1u)) >> 16);
}

// ---------------- deg ----------------
__global__ void calc_deg(const int* __restrict__ dst, float* __restrict__ deg) {
  int e = blockIdx.x * 256 + threadIdx.x;
  if (e < N_EDGES) atomicAdd(&deg[dst[e]], 1.0f);
}

// ---------------- W2 -> WbT (bf16, transposed to [(k,o)][i]) ----------------
// WbT[ko][i] = W2[k][i*HID+o] for k<64 ; bias slice (ko>=8192): b2[i*HID+o].
__global__ void conv_w(const float* __restrict__ W2, const float* __restrict__ b2,
                       unsigned short* __restrict__ WbT, int din, int KP) {
  int idx = blockIdx.x * 256 + threadIdx.x;
  int total = ZCOLS * KP;
  if (idx >= total) return;
  int ko = idx / KP, i = idx % KP;
  int k = ko >> 7, o = ko & 127;
  float v = 0.0f;
  if (i < din) v = (k < 64) ? W2[k * (din * HID) + i * HID + o] : b2[i * HID + o];
  WbT[idx] = f2bf(v);
}

// ---------------- layer-0 input -> bf16 padded [N][32] ----------------
__global__ void conv_x0(const float* __restrict__ h, unsigned short* __restrict__ xb0) {
  int idx = blockIdx.x * 256 + threadIdx.x;
  if (idx >= N_NODES * 32) return;
  int n = idx >> 5, i = idx & 31;
  xb0[idx] = f2bf(i < IN_DIM ? h[n * IN_DIM + i] : 0.0f);
}

// ---------------- edge MLP stage 1: h = relu(e@W1 + b1), fp32 ----------------
__global__ void edge_mlp(const float* __restrict__ efeat, const float* __restrict__ W1,
                         const float* __restrict__ b1, float* __restrict__ h_all) {
  int idx = blockIdx.x * 256 + threadIdx.x;
  if (idx >= N_EDGES * EDGE_H) return;
  int e = idx >> 6, k = idx & 63;
  float acc = b1[k];
#pragma unroll
  for (int j = 0; j < E_DIMF; ++j) acc += efeat[e * E_DIMF + j] * W1[j * EDGE_H + k];
  h_all[idx] = fmaxf(acc, 0.0f);
}

// ---------------- Z GEMM: Z[n, ko] = sum_i xb[n,i] * WbT[ko,i] (bf16 MFMA) -----
// A tile: Xb rows (contiguous), B tile: WbT rows (contiguous). Both [128][KP] in
// LDS with XOR swizzle to avoid the 256B-stride bank conflict on ds_read_b128.
template <int KP, int SWZ>
__global__ __launch_bounds__(256) void gemm_z(const unsigned short* __restrict__ Xb,
                                              const unsigned short* __restrict__ WbT,
                                              unsigned short* __restrict__ Z) {
  extern __shared__ unsigned short lds[];
  unsigned short* Al = lds;              // [128][KP]
  unsigned short* Bl = lds + 128 * KP;   // [128][KP] (row = output col)
  const int nb = blockIdx.x;   // ko tile: 0..64
  const int mb = blockIdx.y;   // node tile: 0..15
  const int t = threadIdx.x;
  const int ROWB = KP * 2;               // bytes per row
  const int NCH = 128 * ROWB / 16;       // 16B chunks per tile
  const unsigned short* Asrc = Xb + (size_t)mb * 128 * KP;
  const unsigned short* Bsrc = WbT + (size_t)nb * 128 * KP;
  for (int c = t; c < NCH; c += 256) {
    int off = c * 16;
    int row = off / ROWB;
    int kb = off % ROWB;
    int dsto = row * ROWB + (kb ^ ((row & SWZ) << 4));
    *(uint4*)((char*)Al + dsto) = *(const uint4*)((const char*)Asrc + off);
    *(uint4*)((char*)Bl + dsto) = *(const uint4*)((const char*)Bsrc + off);
  }
  __syncthreads();

  const int w = t >> 6, l = t & 63;
  const int wm = (w >> 1) * 64, wn = (w & 1) * 64;
  const int lr = l & 15, lh = l >> 4;
  f32x4 acc[4][4] = {};
#pragma unroll
  for (int kk = 0; kk < KP; kk += 32) {
    short8 a[4], b[4];
    const int kb = (kk + lh * 8) * 2;
#pragma unroll
    for (int mi = 0; mi < 4; ++mi) {
      int row = wm + mi * 16 + lr;
      int addr = row * ROWB + (kb ^ ((row & SWZ) << 4));
      a[mi] = *(const short8*)((const char*)Al + addr);
    }
#pragma unroll
    for (int ni = 0; ni < 4; ++ni) {
      int col = wn + ni * 16 + lr;
      int addr = col * ROWB + (kb ^ ((col & SWZ) << 4));
      b[ni] = *(const short8*)((const char*)Bl + addr);
    }
#pragma unroll
    for (int mi = 0; mi < 4; ++mi)
#pragma unroll
      for (int ni = 0; ni < 4; ++ni)
        acc[mi][ni] = __builtin_amdgcn_mfma_f32_16x16x32_bf16(a[mi], b[ni], acc[mi][ni], 0, 0, 0);
  }
  // epilogue: D row = (lane>>4)*4 + r, col = lane&15  [guide §3, m89/m91]
#pragma unroll
  for (int mi = 0; mi < 4; ++mi) {
#pragma unroll
    for (int ni = 0; ni < 4; ++ni) {
#pragma unroll
      for (int r = 0; r < 4; ++r) {
        int grow = mb * 128 + wm + mi * 16 + lh * 4 + r;
        int gcol = nb * 128 + wn + ni * 16 + lr;
        Z[(size_t)grow * ZCOLS + gcol] = f2bf(acc[mi][ni][r]);
      }
    }
  }
}

// ---------------- contract h with Z, scatter-add to agg ----------------
__global__ __launch_bounds__(128) void contract_agg(
    const float* __restrict__ h_all, const unsigned short* __restrict__ Z,
    const int* __restrict__ src, const int* __restrict__ dst,
    float* __restrict__ agg) {
  int e = blockIdx.x;
  int t = threadIdx.x;  // output channel o
  __shared__ float hs[NSLICE];
  if (t <= 64) hs[t] = (t < 64) ? h_all[e * EDGE_H + t] : 1.0f;
  __syncthreads();
  int s = src[e], d = dst[e];
  const unsigned short* zr = Z + (size_t)s * ZCOLS;
  float acc = 0.0f;
  for (int k = 0; k < NSLICE; ++k) acc += hs[k] * bf2f(zr[k * HID + t]);
  atomicAdd(&agg[d * HID + t], acc);
}

// ---------------- finalize: mean-agg + bias -> relu -> BN -> x (f32 + bf16) ----
__global__ void finalize(const float* __restrict__ agg, const float* __restrict__ deg,
                         const float* __restrict__ bias, const float* __restrict__ gamma,
                         const float* __restrict__ beta, const float* __restrict__ mean,
                         const float* __restrict__ var, float* __restrict__ xout,
                         unsigned short* __restrict__ xbout) {
  int idx = blockIdx.x * 256 + threadIdx.x;
  if (idx >= N_NODES * HID) return;
  int n = idx >> 7, o = idx & 127;
  float v = agg[idx] / fmaxf(deg[n], 1.0f) + bias[o];
  v = fmaxf(v, 0.0f);
  v = (v - mean[o]) * rsqrtf(var[o] + BN_EPS) * gamma[o] + beta[o];
  xout[idx] = v;
  xbout[idx] = f2bf(v);
}

// ---------------- readout: per-graph mean (BN'd) and max ----------------
__global__ __launch_bounds__(128) void readout(const float* __restrict__ x,
                                               const int* __restrict__ ng,
                                               const float* __restrict__ g_out,
                                               const float* __restrict__ b_out,
                                               const float* __restrict__ m_out,
                                               const float* __restrict__ v_out,
                                               float* __restrict__ out) {
  int g = blockIdx.x, t = threadIdx.x;
  float sum = 0.0f, mx = -3.4e38f, cnt = 0.0f;
  for (int n = 0; n < N_NODES; ++n) {
    if (ng[n] == g) {
      float v = x[n * HID + t];
      sum += v;
      mx = fmaxf(mx, v);
      cnt += 1.0f;
    }
  }
  float hn = sum / fmaxf(cnt, 1.0f);
  hn = (hn - m_out[t]) * rsqrtf(v_out[t] + BN_EPS) * g_out[t] + b_out[t];
  out[g * 2 * HID + t] = hn;
  out[g * 2 * HID + HID + t] = mx;
}

extern "C" void kernel_launch(void* const* d_in, const int* in_sizes, int n_in,
                              void* d_out, int out_size, void* d_ws, size_t ws_size,
                              hipStream_t stream) {
  const float* h_in   = (const float*)d_in[0];
  const float* e_in   = (const float*)d_in[1];
  const int*   src    = (const int*)d_in[2];
  const int*   dst    = (const int*)d_in[3];
  const int*   ng     = (const int*)d_in[4];
  const float* eW1_0  = (const float*)d_in[5];
  const float* eb1_0  = (const float*)d_in[6];
  const float* eW2_0  = (const float*)d_in[7];
  const float* eb2_0  = (const float*)d_in[8];
  const float* bias_0 = (const float*)d_in[9];
  const float* gamma_0= (const float*)d_in[10];
  const float* beta_0 = (const float*)d_in[11];
  const float* mean_0 = (const float*)d_in[12];
  const float* var_0  = (const float*)d_in[13];
  const float* eW1    = (const float*)d_in[14];
  const float* eb1    = (const float*)d_in[15];
  const float* eW2    = (const float*)d_in[16];
  const float* eb2    = (const float*)d_in[17];
  const float* biasL  = (const float*)d_in[18];
  const float* gammaL = (const float*)d_in[19];
  const float* betaL  = (const float*)d_in[20];
  const float* meanL  = (const float*)d_in[21];
  const float* varL   = (const float*)d_in[22];
  const float* g_out  = (const float*)d_in[23];
  const float* b_out  = (const float*)d_in[24];
  const float* m_out  = (const float*)d_in[25];
  const float* v_out  = (const float*)d_in[26];
  float* out = (float*)d_out;

  char* ws = (char*)d_ws;
  size_t off = 0;
  auto alloc = [&](size_t bytes) {
    void* p = ws + off;
    off = (off + bytes + 255) & ~(size_t)255;
    return p;
  };
  unsigned short* Z    = (unsigned short*)alloc((size_t)N_NODES * ZCOLS * 2);
  unsigned short* WbT0 = (unsigned short*)alloc((size_t)ZCOLS * 32 * 2);
  unsigned short* WbT1 = (unsigned short*)alloc((size_t)ZCOLS * 128 * 2);
  unsigned short* WbT2 = (unsigned short*)alloc((size_t)ZCOLS * 128 * 2);
  unsigned short* WbT3 = (unsigned short*)alloc((size_t)ZCOLS * 128 * 2);
  float* h_all         = (float*)alloc((size_t)N_EDGES * EDGE_H * 4);
  unsigned short* xb0  = (unsigned short*)alloc((size_t)N_NODES * 32 * 2);
  unsigned short* xb   = (unsigned short*)alloc((size_t)N_NODES * HID * 2);
  float* xcur          = (float*)alloc((size_t)N_NODES * HID * 4);
  float* agg           = (float*)alloc((size_t)N_NODES * HID * 4);
  float* deg           = (float*)alloc((size_t)N_NODES * 4);

  // --- one-time per call: deg, weight transposes, layer-0 input cast ---
  hipMemsetAsync(deg, 0, N_NODES * 4, stream);
  calc_deg<<<N_EDGES / 256, 256, 0, stream>>>(dst, deg);
  conv_w<<<(ZCOLS * 32 + 255) / 256, 256, 0, stream>>>(eW2_0, eb2_0, WbT0, IN_DIM, 32);
  conv_w<<<(ZCOLS * 128 + 255) / 256, 256, 0, stream>>>(eW2, eb2, WbT1, HID, 128);
  conv_w<<<(ZCOLS * 128 + 255) / 256, 256, 0, stream>>>(eW2 + 1 * 64 * 16384, eb2 + 1 * 16384, WbT2, HID, 128);
  conv_w<<<(ZCOLS * 128 + 255) / 256, 256, 0, stream>>>(eW2 + 2 * 64 * 16384, eb2 + 2 * 16384, WbT3, HID, 128);
  conv_x0<<<(N_NODES * 32) / 256, 256, 0, stream>>>(h_in, xb0);

  // --- layer 0 (din=11, padded K=32) ---
  edge_mlp<<<(N_EDGES * EDGE_H) / 256, 256, 0, stream>>>(e_in, eW1_0, eb1_0, h_all);
  gemm_z<32, 3><<<dim3(65, 16), 256, 2 * 128 * 32 * 2, stream>>>(xb0, WbT0, Z);
  hipMemsetAsync(agg, 0, (size_t)N_NODES * HID * 4, stream);
  contract_agg<<<N_EDGES, 128, 0, stream>>>(h_all, Z, src, dst, agg);
  finalize<<<(N_NODES * HID) / 256, 256, 0, stream>>>(agg, deg, bias_0, gamma_0, beta_0,
                                                      mean_0, var_0, xcur, xb);

  // --- layers 1..3 (din=128) ---
  for (int l = 0; l < 3; ++l) {
    const unsigned short* W = (l == 0) ? WbT1 : (l == 1) ? WbT2 : WbT3;
    edge_mlp<<<(N_EDGES * EDGE_H) / 256, 256, 0, stream>>>(e_in, eW1 + l * E_DIMF * EDGE_H,
                                                           eb1 + l * EDGE_H, h_all);
    gemm_z<128, 7><<<dim3(65, 16), 256, 2 * 128 * 128 * 2, stream>>>(xb, W, Z);
    hipMemsetAsync(agg, 0, (size_t)N_NODES * HID * 4, stream);
    contract_agg<<<N_EDGES, 128, 0, stream>>>(h_all, Z, src, dst, agg);
    finalize<<<(N_NODES * HID) / 256, 256, 0, stream>>>(agg, deg, biasL + l * HID,
                                                        gammaL + l * HID, betaL + l * HID,
                                                        meanL + l * HID, varL + l * HID,
                                                        xcur, xb);
  }

  readout<<<N_GRAPH, 128, 0, stream>>>(xcur, ng, g_out, b_out, m_out, v_out, out);
}

// Round 2
// 209.540 us; speedup vs baseline: 1.4484x; 1.4484x over previous
//
#include <hip/hip_runtime.h>
#include <stdint.h>

#define N_NODES 2048
#define N_EDGES 4096
#define N_GRAPH 16
#define IN_DIM  11
#define HID     128
#define E_DIMF  6
#define EDGE_H  64
#define NSLICE  65            // 64 h-slices + 1 bias slice
#define ZCOLS   (NSLICE*HID)  // 8320
#define BN_EPS  1e-5f

typedef __attribute__((ext_vector_type(8))) short short8;
typedef __attribute__((ext_vector_type(4))) float f32x4;

static __device__ __forceinline__ float bf2f(unsigned short u) {
  union { float f; uint32_t i; } x; x.i = ((uint32_t)u) << 16; return x.f;
}
static __device__ __forceinline__ unsigned short f2bf(float f) {
  union { float f; uint32_t i; } x; x.f = f;
  uint32_t i = x.i;
  return (unsigned short)((i + 0x7FFFu + ((i >> 16) & 1u)) >> 16);
}

// ---------------- deg ----------------
__global__ void calc_deg(const int* __restrict__ dst, float* __restrict__ deg) {
  int e = blockIdx.x * 256 + threadIdx.x;
  if (e < N_EDGES) atomicAdd(&deg[dst[e]], 1.0f);
}

// ---- W2 -> WbT (bf16, [(k,o)][i]) via LDS-tiled transpose, coalesced ----
// block = one k-slab (k<64: W2[k][i][o]; k==64: bias slab b2[i][o]).
// WbT[(k*128+o)*KP + i] = slab[i][o]  (i>=din padded with 0).
template <int KP>
__global__ __launch_bounds__(256) void conv_w_t(const float* __restrict__ W2,
                                                const float* __restrict__ b2,
                                                unsigned short* __restrict__ WbT,
                                                int din) {
  __shared__ unsigned short tile[128 * 130];  // [i][o], pad 130 -> bank stride 65 (odd)
  const int k = blockIdx.x;  // 0..64
  const float* src = (k < 64) ? (W2 + (size_t)k * din * HID) : b2;
  const int t = threadIdx.x;
  for (int j = t; j < din * HID; j += 256) {   // coalesced fp32 reads
    int i = j >> 7, o = j & 127;
    tile[i * 130 + o] = f2bf(src[j]);
  }
  __syncthreads();
  for (int j = t; j < HID * KP; j += 256) {    // coalesced bf16 writes
    int o = j / KP, i = j & (KP - 1);
    unsigned short v = (i < din) ? tile[i * 130 + o] : (unsigned short)0;
    WbT[((size_t)k * HID + o) * KP + i] = v;
  }
}

// ---------------- layer-0 input -> bf16 padded [N][32] ----------------
__global__ void conv_x0(const float* __restrict__ h, unsigned short* __restrict__ xb0) {
  int idx = blockIdx.x * 256 + threadIdx.x;
  if (idx >= N_NODES * 32) return;
  int n = idx >> 5, i = idx & 31;
  xb0[idx] = f2bf(i < IN_DIM ? h[n * IN_DIM + i] : 0.0f);
}

// ---------------- edge MLP stage 1: h = relu(e@W1 + b1), fp32 ----------------
__global__ void edge_mlp(const float* __restrict__ efeat, const float* __restrict__ W1,
                         const float* __restrict__ b1, float* __restrict__ h_all) {
  int idx = blockIdx.x * 256 + threadIdx.x;
  if (idx >= N_EDGES * EDGE_H) return;
  int e = idx >> 6, k = idx & 63;
  float acc = b1[k];
#pragma unroll
  for (int j = 0; j < E_DIMF; ++j) acc += efeat[e * E_DIMF + j] * W1[j * EDGE_H + k];
  h_all[idx] = fmaxf(acc, 0.0f);
}

// ---------------- Z GEMM: Z[n, ko] = sum_i xb[n,i] * WbT[ko,i] (bf16 MFMA) -----
template <int KP, int SWZ>
__global__ __launch_bounds__(256) void gemm_z(const unsigned short* __restrict__ Xb,
                                              const unsigned short* __restrict__ WbT,
                                              unsigned short* __restrict__ Z) {
  extern __shared__ unsigned short lds[];
  unsigned short* Al = lds;              // [128][KP]
  unsigned short* Bl = lds + 128 * KP;   // [128][KP] (row = output col)
  const int nb = blockIdx.x;   // ko tile: 0..64
  const int mb = blockIdx.y;   // node tile: 0..15
  const int t = threadIdx.x;
  const int ROWB = KP * 2;               // bytes per row
  const int NCH = 128 * ROWB / 16;       // 16B chunks per tile
  const unsigned short* Asrc = Xb + (size_t)mb * 128 * KP;
  const unsigned short* Bsrc = WbT + (size_t)nb * 128 * KP;
  for (int c = t; c < NCH; c += 256) {
    int off = c * 16;
    int row = off / ROWB;
    int kb = off % ROWB;
    int dsto = row * ROWB + (kb ^ ((row & SWZ) << 4));
    *(uint4*)((char*)Al + dsto) = *(const uint4*)((const char*)Asrc + off);
    *(uint4*)((char*)Bl + dsto) = *(const uint4*)((const char*)Bsrc + off);
  }
  __syncthreads();

  const int w = t >> 6, l = t & 63;
  const int wm = (w >> 1) * 64, wn = (w & 1) * 64;
  const int lr = l & 15, lh = l >> 4;
  f32x4 acc[4][4] = {};
#pragma unroll
  for (int kk = 0; kk < KP; kk += 32) {
    short8 a[4], b[4];
    const int kb = (kk + lh * 8) * 2;
#pragma unroll
    for (int mi = 0; mi < 4; ++mi) {
      int row = wm + mi * 16 + lr;
      int addr = row * ROWB + (kb ^ ((row & SWZ) << 4));
      a[mi] = *(const short8*)((const char*)Al + addr);
    }
#pragma unroll
    for (int ni = 0; ni < 4; ++ni) {
      int col = wn + ni * 16 + lr;
      int addr = col * ROWB + (kb ^ ((col & SWZ) << 4));
      b[ni] = *(const short8*)((const char*)Bl + addr);
    }
#pragma unroll
    for (int mi = 0; mi < 4; ++mi)
#pragma unroll
      for (int ni = 0; ni < 4; ++ni)
        acc[mi][ni] = __builtin_amdgcn_mfma_f32_16x16x32_bf16(a[mi], b[ni], acc[mi][ni], 0, 0, 0);
  }
  // epilogue: D row = (lane>>4)*4 + r, col = lane&15  [guide §3, m89/m91]
#pragma unroll
  for (int mi = 0; mi < 4; ++mi) {
#pragma unroll
    for (int ni = 0; ni < 4; ++ni) {
#pragma unroll
      for (int r = 0; r < 4; ++r) {
        int grow = mb * 128 + wm + mi * 16 + lh * 4 + r;
        int gcol = nb * 128 + wn + ni * 16 + lr;
        Z[(size_t)grow * ZCOLS + gcol] = f2bf(acc[mi][ni][r]);
      }
    }
  }
}

// ---------------- contract h with Z, scatter-add to agg ----------------
__global__ __launch_bounds__(128) void contract_agg(
    const float* __restrict__ h_all, const unsigned short* __restrict__ Z,
    const int* __restrict__ src, const int* __restrict__ dst,
    float* __restrict__ agg) {
  int e = blockIdx.x;
  int t = threadIdx.x;  // output channel o
  __shared__ float hs[NSLICE];
  if (t <= 64) hs[t] = (t < 64) ? h_all[e * EDGE_H + t] : 1.0f;
  __syncthreads();
  int s = src[e], d = dst[e];
  const unsigned short* zr = Z + (size_t)s * ZCOLS;
  float acc = 0.0f;
  for (int k = 0; k < NSLICE; ++k) acc += hs[k] * bf2f(zr[k * HID + t]);
  atomicAdd(&agg[d * HID + t], acc);
}

// ---------------- finalize: mean-agg + bias -> relu -> BN -> x (f32 + bf16) ----
__global__ void finalize(const float* __restrict__ agg, const float* __restrict__ deg,
                         const float* __restrict__ bias, const float* __restrict__ gamma,
                         const float* __restrict__ beta, const float* __restrict__ mean,
                         const float* __restrict__ var, float* __restrict__ xout,
                         unsigned short* __restrict__ xbout) {
  int idx = blockIdx.x * 256 + threadIdx.x;
  if (idx >= N_NODES * HID) return;
  int n = idx >> 7, o = idx & 127;
  float v = agg[idx] / fmaxf(deg[n], 1.0f) + bias[o];
  v = fmaxf(v, 0.0f);
  v = (v - mean[o]) * rsqrtf(var[o] + BN_EPS) * gamma[o] + beta[o];
  xout[idx] = v;
  xbout[idx] = f2bf(v);
}

// ---------------- parallel readout: atomic sum + max per (graph, channel) -----
// monotonic uint key for float atomicMax: neg -> ~bits, pos -> bits|0x80000000.
__global__ void readout_accum(const float* __restrict__ x, const int* __restrict__ ng,
                              float* __restrict__ gsum, unsigned int* __restrict__ gmax,
                              float* __restrict__ gcnt) {
  int idx = blockIdx.x * 256 + threadIdx.x;
  if (idx >= N_NODES * HID) return;
  int n = idx >> 7, o = idx & 127;
  int g = ng[n];
  float v = x[idx];
  atomicAdd(&gsum[g * HID + o], v);
  unsigned int u = __float_as_uint(v);
  unsigned int key = (u & 0x80000000u) ? ~u : (u | 0x80000000u);
  atomicMax(&gmax[g * HID + o], key);
  if (o == 0) atomicAdd(&gcnt[g], 1.0f);
}

__global__ void out_final(const float* __restrict__ gsum, const unsigned int* __restrict__ gmax,
                          const float* __restrict__ gcnt,
                          const float* __restrict__ g_out, const float* __restrict__ b_out,
                          const float* __restrict__ m_out, const float* __restrict__ v_out,
                          float* __restrict__ out) {
  int g = blockIdx.x, t = threadIdx.x;
  float hn = gsum[g * HID + t] / fmaxf(gcnt[g], 1.0f);
  hn = (hn - m_out[t]) * rsqrtf(v_out[t] + BN_EPS) * g_out[t] + b_out[t];
  unsigned int key = gmax[g * HID + t];
  unsigned int u = (key & 0x80000000u) ? (key ^ 0x80000000u) : ~key;
  out[g * 2 * HID + t] = hn;
  out[g * 2 * HID + HID + t] = __uint_as_float(u);
}

extern "C" void kernel_launch(void* const* d_in, const int* in_sizes, int n_in,
                              void* d_out, int out_size, void* d_ws, size_t ws_size,
                              hipStream_t stream) {
  const float* h_in   = (const float*)d_in[0];
  const float* e_in   = (const float*)d_in[1];
  const int*   src    = (const int*)d_in[2];
  const int*   dst    = (const int*)d_in[3];
  const int*   ng     = (const int*)d_in[4];
  const float* eW1_0  = (const float*)d_in[5];
  const float* eb1_0  = (const float*)d_in[6];
  const float* eW2_0  = (const float*)d_in[7];
  const float* eb2_0  = (const float*)d_in[8];
  const float* bias_0 = (const float*)d_in[9];
  const float* gamma_0= (const float*)d_in[10];
  const float* beta_0 = (const float*)d_in[11];
  const float* mean_0 = (const float*)d_in[12];
  const float* var_0  = (const float*)d_in[13];
  const float* eW1    = (const float*)d_in[14];
  const float* eb1    = (const float*)d_in[15];
  const float* eW2    = (const float*)d_in[16];
  const float* eb2    = (const float*)d_in[17];
  const float* biasL  = (const float*)d_in[18];
  const float* gammaL = (const float*)d_in[19];
  const float* betaL  = (const float*)d_in[20];
  const float* meanL  = (const float*)d_in[21];
  const float* varL   = (const float*)d_in[22];
  const float* g_out  = (const float*)d_in[23];
  const float* b_out  = (const float*)d_in[24];
  const float* m_out  = (const float*)d_in[25];
  const float* v_out  = (const float*)d_in[26];
  float* out = (float*)d_out;

  char* ws = (char*)d_ws;
  size_t off = 0;
  auto alloc = [&](size_t bytes) {
    void* p = ws + off;
    off = (off + bytes + 255) & ~(size_t)255;
    return p;
  };
  unsigned short* Z    = (unsigned short*)alloc((size_t)N_NODES * ZCOLS * 2);
  unsigned short* WbT0 = (unsigned short*)alloc((size_t)ZCOLS * 32 * 2);
  unsigned short* WbT1 = (unsigned short*)alloc((size_t)ZCOLS * 128 * 2);
  unsigned short* WbT2 = (unsigned short*)alloc((size_t)ZCOLS * 128 * 2);
  unsigned short* WbT3 = (unsigned short*)alloc((size_t)ZCOLS * 128 * 2);
  float* h_all         = (float*)alloc((size_t)N_EDGES * EDGE_H * 4);
  unsigned short* xb0  = (unsigned short*)alloc((size_t)N_NODES * 32 * 2);
  unsigned short* xb   = (unsigned short*)alloc((size_t)N_NODES * HID * 2);
  float* xcur          = (float*)alloc((size_t)N_NODES * HID * 4);
  float* agg           = (float*)alloc((size_t)N_NODES * HID * 4);
  float* deg           = (float*)alloc((size_t)N_NODES * 4);
  // graph accumulators: gsum | gmax | gcnt contiguous for one memset
  float* gsum          = (float*)alloc((size_t)N_GRAPH * HID * 4);
  unsigned int* gmax   = (unsigned int*)alloc((size_t)N_GRAPH * HID * 4);
  float* gcnt          = (float*)alloc((size_t)N_GRAPH * 4);

  // --- one-time per call: deg, weight transposes, layer-0 input cast ---
  hipMemsetAsync(deg, 0, N_NODES * 4, stream);
  hipMemsetAsync(gsum, 0, (size_t)(N_GRAPH * HID * 8 + 256 + N_GRAPH * 4), stream);
  calc_deg<<<N_EDGES / 256, 256, 0, stream>>>(dst, deg);
  conv_w_t<32><<<65, 256, 0, stream>>>(eW2_0, eb2_0, WbT0, IN_DIM);
  conv_w_t<128><<<65, 256, 0, stream>>>(eW2, eb2, WbT1, HID);
  conv_w_t<128><<<65, 256, 0, stream>>>(eW2 + 1 * 64 * (HID * HID) / 1, eb2 + 1 * (HID * HID), WbT2, HID);
  conv_w_t<128><<<65, 256, 0, stream>>>(eW2 + 2 * 64 * (HID * HID), eb2 + 2 * (HID * HID), WbT3, HID);
  conv_x0<<<(N_NODES * 32) / 256, 256, 0, stream>>>(h_in, xb0);

  // --- layer 0 (din=11, padded K=32) ---
  edge_mlp<<<(N_EDGES * EDGE_H) / 256, 256, 0, stream>>>(e_in, eW1_0, eb1_0, h_all);
  gemm_z<32, 3><<<dim3(65, 16), 256, 2 * 128 * 32 * 2, stream>>>(xb0, WbT0, Z);
  hipMemsetAsync(agg, 0, (size_t)N_NODES * HID * 4, stream);
  contract_agg<<<N_EDGES, 128, 0, stream>>>(h_all, Z, src, dst, agg);
  finalize<<<(N_NODES * HID) / 256, 256, 0, stream>>>(agg, deg, bias_0, gamma_0, beta_0,
                                                      mean_0, var_0, xcur, xb);

  // --- layers 1..3 (din=128) ---
  for (int l = 0; l < 3; ++l) {
    const unsigned short* W = (l == 0) ? WbT1 : (l == 1) ? WbT2 : WbT3;
    edge_mlp<<<(N_EDGES * EDGE_H) / 256, 256, 0, stream>>>(e_in, eW1 + l * E_DIMF * EDGE_H,
                                                           eb1 + l * EDGE_H, h_all);
    gemm_z<128, 7><<<dim3(65, 16), 256, 2 * 128 * 128 * 2, stream>>>(xb, W, Z);
    hipMemsetAsync(agg, 0, (size_t)N_NODES * HID * 4, stream);
    contract_agg<<<N_EDGES, 128, 0, stream>>>(h_all, Z, src, dst, agg);
    finalize<<<(N_NODES * HID) / 256, 256, 0, stream>>>(agg, deg, biasL + l * HID,
                                                        gammaL + l * HID, betaL + l * HID,
                                                        meanL + l * HID, varL + l * HID,
                                                        xcur, xb);
  }

  // --- readout ---
  readout_accum<<<(N_NODES * HID) / 256, 256, 0, stream>>>(xcur, ng, gsum, gmax, gcnt);
  out_final<<<N_GRAPH, HID, 0, stream>>>(gsum, gmax, gcnt, g_out, b_out, m_out, v_out, out);
}

// Round 3
// 202.483 us; speedup vs baseline: 1.4989x; 1.0348x over previous
//
#include <hip/hip_runtime.h>
#include <stdint.h>

#define N_NODES 2048
#define N_EDGES 4096
#define N_GRAPH 16
#define IN_DIM  11
#define HID     128
#define E_DIMF  6
#define EDGE_H  64
#define NSLICE  65            // 64 h-slices + 1 bias slice
#define ZCOLS   (NSLICE*HID)  // 8320
#define BN_EPS  1e-5f

typedef __attribute__((ext_vector_type(8))) short short8;
typedef __attribute__((ext_vector_type(4))) float f32x4;

static __device__ __forceinline__ float bf2f(unsigned short u) {
  union { float f; uint32_t i; } x; x.i = ((uint32_t)u) << 16; return x.f;
}
static __device__ __forceinline__ unsigned short f2bf(float f) {
  union { float f; uint32_t i; } x; x.f = f;
  uint32_t i = x.i;
  return (unsigned short)((i + 0x7FFFu + ((i >> 16) & 1u)) >> 16);
}

// ---------------- CSR build: deg (int) ----------------
__global__ void calc_deg_i(const int* __restrict__ dst, int* __restrict__ degi) {
  int e = blockIdx.x * 256 + threadIdx.x;
  if (e < N_EDGES) atomicAdd(&degi[dst[e]], 1);
}

// 1 block, 256 threads, 8 nodes/thread: exclusive scan -> roff[0..N], cursor
__global__ __launch_bounds__(256) void build_offsets(const int* __restrict__ degi,
                                                     int* __restrict__ roff,
                                                     int* __restrict__ cursor) {
  __shared__ int part[256];
  int t = threadIdx.x;
  int base = t * 8;
  int loc[8];
  int s = 0;
#pragma unroll
  for (int j = 0; j < 8; ++j) { loc[j] = s; s += degi[base + j]; }
  part[t] = s;
  __syncthreads();
  int pre = 0;
  for (int i = 0; i < t; ++i) pre += part[i];
#pragma unroll
  for (int j = 0; j < 8; ++j) {
    int v = pre + loc[j];
    roff[base + j] = v;
    cursor[base + j] = v;
  }
  if (t == 255) roff[N_NODES] = pre + s;
}

__global__ void scatter_edges(const int* __restrict__ dst, int* __restrict__ cursor,
                              int* __restrict__ elist) {
  int e = blockIdx.x * 256 + threadIdx.x;
  if (e < N_EDGES) {
    int pos = atomicAdd(&cursor[dst[e]], 1);
    elist[pos] = e;
  }
}

// ---- W2 -> WbT (bf16, [(k,o)][i]) via LDS-tiled transpose, coalesced ----
// layer 0: KP=32, din=11.  WbT[(k*128+o)*KP+i] = slab_k[i][o], zero-padded.
__global__ __launch_bounds__(256) void conv_w0(const float* __restrict__ W2,
                                               const float* __restrict__ b2,
                                               unsigned short* __restrict__ WbT) {
  __shared__ unsigned short tile[128 * 130];
  const int k = blockIdx.x;  // 0..64
  const float* src = (k < 64) ? (W2 + (size_t)k * IN_DIM * HID) : b2;
  const int t = threadIdx.x;
  for (int j = t; j < IN_DIM * HID; j += 256) {
    int i = j >> 7, o = j & 127;
    tile[i * 130 + o] = f2bf(src[j]);
  }
  __syncthreads();
  for (int j = t; j < HID * 32; j += 256) {
    int o = j >> 5, i = j & 31;
    unsigned short v = (i < IN_DIM) ? tile[i * 130 + o] : (unsigned short)0;
    WbT[((size_t)k * HID + o) * 32 + i] = v;
  }
}

// layers 1..3 in one launch: grid (65, 3)
__global__ __launch_bounds__(256) void conv_wL(const float* __restrict__ W2,
                                               const float* __restrict__ b2,
                                               unsigned short* __restrict__ WbT) {
  __shared__ unsigned short tile[128 * 130];
  const int k = blockIdx.x, l = blockIdx.y;
  const float* src = (k < 64) ? (W2 + ((size_t)l * 64 + k) * (HID * HID))
                              : (b2 + (size_t)l * (HID * HID));
  unsigned short* dstp = WbT + (size_t)l * ZCOLS * HID;
  const int t = threadIdx.x;
  for (int j = t; j < HID * HID; j += 256) {
    int i = j >> 7, o = j & 127;
    tile[i * 130 + o] = f2bf(src[j]);
  }
  __syncthreads();
  for (int j = t; j < HID * HID; j += 256) {
    int o = j >> 7, i = j & 127;
    dstp[((size_t)k * HID + o) * HID + i] = tile[i * 130 + o];
  }
}

// ---------------- layer-0 input -> bf16 padded [N][32] ----------------
__global__ void conv_x0(const float* __restrict__ h, unsigned short* __restrict__ xb0) {
  int idx = blockIdx.x * 256 + threadIdx.x;
  if (idx >= N_NODES * 32) return;
  int n = idx >> 5, i = idx & 31;
  xb0[idx] = f2bf(i < IN_DIM ? h[n * IN_DIM + i] : 0.0f);
}

// ---------------- Z GEMM: Z[n, ko] = sum_i xb[n,i] * WbT[ko,i] (bf16 MFMA) -----
template <int KP, int SWZ>
__global__ __launch_bounds__(256) void gemm_z(const unsigned short* __restrict__ Xb,
                                              const unsigned short* __restrict__ WbT,
                                              unsigned short* __restrict__ Z) {
  extern __shared__ unsigned short lds[];
  unsigned short* Al = lds;              // [128][KP]
  unsigned short* Bl = lds + 128 * KP;   // [128][KP] (row = output col)
  const int nb = blockIdx.x;   // ko tile: 0..64
  const int mb = blockIdx.y;   // node tile: 0..15
  const int t = threadIdx.x;
  const int ROWB = KP * 2;               // bytes per row
  const int NCH = 128 * ROWB / 16;       // 16B chunks per tile
  const unsigned short* Asrc = Xb + (size_t)mb * 128 * KP;
  const unsigned short* Bsrc = WbT + (size_t)nb * 128 * KP;
  for (int c = t; c < NCH; c += 256) {
    int off = c * 16;
    int row = off / ROWB;
    int kb = off % ROWB;
    int dsto = row * ROWB + (kb ^ ((row & SWZ) << 4));
    *(uint4*)((char*)Al + dsto) = *(const uint4*)((const char*)Asrc + off);
    *(uint4*)((char*)Bl + dsto) = *(const uint4*)((const char*)Bsrc + off);
  }
  __syncthreads();

  const int w = t >> 6, l = t & 63;
  const int wm = (w >> 1) * 64, wn = (w & 1) * 64;
  const int lr = l & 15, lh = l >> 4;
  f32x4 acc[4][4] = {};
#pragma unroll
  for (int kk = 0; kk < KP; kk += 32) {
    short8 a[4], b[4];
    const int kb = (kk + lh * 8) * 2;
#pragma unroll
    for (int mi = 0; mi < 4; ++mi) {
      int row = wm + mi * 16 + lr;
      int addr = row * ROWB + (kb ^ ((row & SWZ) << 4));
      a[mi] = *(const short8*)((const char*)Al + addr);
    }
#pragma unroll
    for (int ni = 0; ni < 4; ++ni) {
      int col = wn + ni * 16 + lr;
      int addr = col * ROWB + (kb ^ ((col & SWZ) << 4));
      b[ni] = *(const short8*)((const char*)Bl + addr);
    }
#pragma unroll
    for (int mi = 0; mi < 4; ++mi)
#pragma unroll
      for (int ni = 0; ni < 4; ++ni)
        acc[mi][ni] = __builtin_amdgcn_mfma_f32_16x16x32_bf16(a[mi], b[ni], acc[mi][ni], 0, 0, 0);
  }
  // epilogue: D row = (lane>>4)*4 + r, col = lane&15  [guide §3, m89/m91]
#pragma unroll
  for (int mi = 0; mi < 4; ++mi) {
#pragma unroll
    for (int ni = 0; ni < 4; ++ni) {
#pragma unroll
      for (int r = 0; r < 4; ++r) {
        int grow = mb * 128 + wm + mi * 16 + lh * 4 + r;
        int gcol = nb * 128 + wn + ni * 16 + lr;
        Z[(size_t)grow * ZCOLS + gcol] = f2bf(acc[mi][ni][r]);
      }
    }
  }
}

// ------- per-node gather: edge-MLP + contract + mean + bias + ReLU + BN -------
// block = node (grid 2048), 128 threads (t = output channel).
template <int LAST>
__global__ __launch_bounds__(128) void node_gather(
    const float* __restrict__ efeat, const float* __restrict__ W1,
    const float* __restrict__ b1, const unsigned short* __restrict__ Z,
    const int* __restrict__ elist, const int* __restrict__ roff,
    const int* __restrict__ src,
    const float* __restrict__ bias, const float* __restrict__ gamma,
    const float* __restrict__ beta, const float* __restrict__ mean,
    const float* __restrict__ var,
    unsigned short* __restrict__ xbout,
    const int* __restrict__ ng, float* __restrict__ gsum,
    unsigned int* __restrict__ gmax, float* __restrict__ gcnt) {
  const int n = blockIdx.x, t = threadIdx.x;
  const int start = roff[n], end = roff[n + 1];
  __shared__ float hs[NSLICE + 1];
  float a0 = 0.f, a1 = 0.f, a2 = 0.f, a3 = 0.f;
  for (int idx = start; idx < end; ++idx) {
    const int e = elist[idx];
    if (t < EDGE_H) {
      float a = b1[t];
#pragma unroll
      for (int j = 0; j < E_DIMF; ++j) a += efeat[e * E_DIMF + j] * W1[j * EDGE_H + t];
      hs[t] = fmaxf(a, 0.f);
    } else if (t == EDGE_H) {
      hs[EDGE_H] = 1.f;
    }
    __syncthreads();
    const unsigned short* zr = Z + (size_t)src[e] * ZCOLS;
#pragma unroll 4
    for (int k = 0; k < 64; k += 4) {
      a0 += hs[k + 0] * bf2f(zr[(k + 0) * HID + t]);
      a1 += hs[k + 1] * bf2f(zr[(k + 1) * HID + t]);
      a2 += hs[k + 2] * bf2f(zr[(k + 2) * HID + t]);
      a3 += hs[k + 3] * bf2f(zr[(k + 3) * HID + t]);
    }
    a0 += bf2f(zr[64 * HID + t]);  // bias slice, h = 1
    __syncthreads();
  }
  const int dg = end - start;
  float v = (a0 + a1 + a2 + a3) / (float)(dg > 0 ? dg : 1) + bias[t];
  v = fmaxf(v, 0.f);
  v = (v - mean[t]) * rsqrtf(var[t] + BN_EPS) * gamma[t] + beta[t];
  if (!LAST) {
    xbout[n * HID + t] = f2bf(v);
  } else {
    const int g = ng[n];
    atomicAdd(&gsum[g * HID + t], v);
    unsigned int u = __float_as_uint(v);
    unsigned int key = (u & 0x80000000u) ? ~u : (u | 0x80000000u);
    atomicMax(&gmax[g * HID + t], key);
    if (t == 0) atomicAdd(&gcnt[g], 1.f);
  }
}

// ---------------- output BN + max decode ----------------
__global__ void out_final(const float* __restrict__ gsum, const unsigned int* __restrict__ gmax,
                          const float* __restrict__ gcnt,
                          const float* __restrict__ g_out, const float* __restrict__ b_out,
                          const float* __restrict__ m_out, const float* __restrict__ v_out,
                          float* __restrict__ out) {
  int g = blockIdx.x, t = threadIdx.x;
  float hn = gsum[g * HID + t] / fmaxf(gcnt[g], 1.0f);
  hn = (hn - m_out[t]) * rsqrtf(v_out[t] + BN_EPS) * g_out[t] + b_out[t];
  unsigned int key = gmax[g * HID + t];
  unsigned int u = (key & 0x80000000u) ? (key ^ 0x80000000u) : ~key;
  out[g * 2 * HID + t] = hn;
  out[g * 2 * HID + HID + t] = __uint_as_float(u);
}

extern "C" void kernel_launch(void* const* d_in, const int* in_sizes, int n_in,
                              void* d_out, int out_size, void* d_ws, size_t ws_size,
                              hipStream_t stream) {
  const float* h_in   = (const float*)d_in[0];
  const float* e_in   = (const float*)d_in[1];
  const int*   src    = (const int*)d_in[2];
  const int*   dst    = (const int*)d_in[3];
  const int*   ng     = (const int*)d_in[4];
  const float* eW1_0  = (const float*)d_in[5];
  const float* eb1_0  = (const float*)d_in[6];
  const float* eW2_0  = (const float*)d_in[7];
  const float* eb2_0  = (const float*)d_in[8];
  const float* bias_0 = (const float*)d_in[9];
  const float* gamma_0= (const float*)d_in[10];
  const float* beta_0 = (const float*)d_in[11];
  const float* mean_0 = (const float*)d_in[12];
  const float* var_0  = (const float*)d_in[13];
  const float* eW1    = (const float*)d_in[14];
  const float* eb1    = (const float*)d_in[15];
  const float* eW2    = (const float*)d_in[16];
  const float* eb2    = (const float*)d_in[17];
  const float* biasL  = (const float*)d_in[18];
  const float* gammaL = (const float*)d_in[19];
  const float* betaL  = (const float*)d_in[20];
  const float* meanL  = (const float*)d_in[21];
  const float* varL   = (const float*)d_in[22];
  const float* g_out  = (const float*)d_in[23];
  const float* b_out  = (const float*)d_in[24];
  const float* m_out  = (const float*)d_in[25];
  const float* v_out  = (const float*)d_in[26];
  float* out = (float*)d_out;

  char* ws = (char*)d_ws;
  size_t off = 0;
  auto alloc = [&](size_t bytes) {
    void* p = ws + off;
    off = (off + bytes + 255) & ~(size_t)255;
    return p;
  };
  unsigned short* Z    = (unsigned short*)alloc((size_t)N_NODES * ZCOLS * 2);
  unsigned short* WbT0 = (unsigned short*)alloc((size_t)ZCOLS * 32 * 2);
  unsigned short* WbTL = (unsigned short*)alloc((size_t)3 * ZCOLS * HID * 2);
  unsigned short* xb0  = (unsigned short*)alloc((size_t)N_NODES * 32 * 2);
  unsigned short* xb   = (unsigned short*)alloc((size_t)N_NODES * HID * 2);
  // zero-region (single memset): gsum | gmax | gcnt | degi
  float* gsum          = (float*)alloc((size_t)N_GRAPH * HID * 4);
  unsigned int* gmax   = (unsigned int*)alloc((size_t)N_GRAPH * HID * 4);
  float* gcnt          = (float*)alloc((size_t)N_GRAPH * 4);
  int*   degi          = (int*)alloc((size_t)N_NODES * 4);
  size_t zbytes = (size_t)((char*)(degi + N_NODES) - (char*)gsum);
  // CSR (no zeroing needed)
  int* roff            = (int*)alloc((size_t)(N_NODES + 1) * 4);
  int* cursor          = (int*)alloc((size_t)N_NODES * 4);
  int* elist           = (int*)alloc((size_t)N_EDGES * 4);

  // --- one-time per call ---
  hipMemsetAsync(gsum, 0, zbytes, stream);
  calc_deg_i<<<N_EDGES / 256, 256, 0, stream>>>(dst, degi);
  build_offsets<<<1, 256, 0, stream>>>(degi, roff, cursor);
  scatter_edges<<<N_EDGES / 256, 256, 0, stream>>>(dst, cursor, elist);
  conv_w0<<<65, 256, 0, stream>>>(eW2_0, eb2_0, WbT0);
  conv_wL<<<dim3(65, 3), 256, 0, stream>>>(eW2, eb2, WbTL);
  conv_x0<<<(N_NODES * 32) / 256, 256, 0, stream>>>(h_in, xb0);

  // --- layer 0 (din=11, padded K=32) ---
  gemm_z<32, 3><<<dim3(65, 16), 256, 2 * 128 * 32 * 2, stream>>>(xb0, WbT0, Z);
  node_gather<0><<<N_NODES, 128, 0, stream>>>(e_in, eW1_0, eb1_0, Z, elist, roff, src,
                                              bias_0, gamma_0, beta_0, mean_0, var_0,
                                              xb, ng, gsum, gmax, gcnt);

  // --- layers 1..3 (din=128) ---
  for (int l = 0; l < 3; ++l) {
    gemm_z<128, 7><<<dim3(65, 16), 256, 2 * 128 * 128 * 2, stream>>>(
        xb, WbTL + (size_t)l * ZCOLS * HID, Z);
    if (l < 2) {
      node_gather<0><<<N_NODES, 128, 0, stream>>>(
          e_in, eW1 + l * E_DIMF * EDGE_H, eb1 + l * EDGE_H, Z, elist, roff, src,
          biasL + l * HID, gammaL + l * HID, betaL + l * HID, meanL + l * HID,
          varL + l * HID, xb, ng, gsum, gmax, gcnt);
    } else {
      node_gather<1><<<N_NODES, 128, 0, stream>>>(
          e_in, eW1 + l * E_DIMF * EDGE_H, eb1 + l * EDGE_H, Z, elist, roff, src,
          biasL + l * HID, gammaL + l * HID, betaL + l * HID, meanL + l * HID,
          varL + l * HID, xb, ng, gsum, gmax, gcnt);
    }
  }

  out_final<<<N_GRAPH, HID, 0, stream>>>(gsum, gmax, gcnt, g_out, b_out, m_out, v_out, out);
}